// Round 8
// baseline (121.549 us; speedup 1.0000x reference)
//
#include <hip/hip_runtime.h>
#include <math.h>

#define HWPIX 4096
#define CKTOT 2304
#define VSTR  40            // V row stride in shorts (80 B)
#define PH    66            // padded feat spatial dim
#define PHW   4356          // 66*66
#define VBUF  (288 * VSTR)  // one V buffer in shorts (23040 B)

typedef __attribute__((ext_vector_type(8))) short short8;
typedef __attribute__((ext_vector_type(2))) float float2v;
typedef __attribute__((ext_vector_type(4))) float float4v;

__device__ __forceinline__ unsigned short f2bf(float f) {
    unsigned u = __float_as_uint(f);
    unsigned r = (u + 0x7FFFu + ((u >> 16) & 1u)) >> 16;   // RNE
    return (unsigned short)r;
}
__device__ __forceinline__ float bf2f(unsigned short h) {
    return __uint_as_float(((unsigned)h) << 16);
}
// hardware packed f32->2xbf16 (RNE), lo=a, hi=b — no builtin on gfx950
__device__ __forceinline__ unsigned cvtpk_bf16(float a, float b) {
    unsigned r;
    asm("v_cvt_pk_bf16_f32 %0, %1, %2" : "=v"(r) : "v"(a), "v"(b));
    return r;
}
// unpack u32 (2x bf16) -> float2 {lo, hi}
__device__ __forceinline__ float2v unpk(unsigned u) {
    float2v r;
    r.x = __uint_as_float(u << 16);
    r.y = __uint_as_float(u & 0xffff0000u);
    return r;
}

// ---------------------------------------------------------------------------
// prep (unchanged from round 6 — verified): blockIdx regions:
//   [0,4096)      x -> xTh / feat -> fh transposes (8B vectorized bf16 stores)
//   [4096,5248)   wpack   (w_dcn -> whi, 2 elems/thread, 4B stores)
//   [5248,5536)   wpack_om(w_offset_mask -> wohi, M=32 padded)
//   [5536,6056)   zero fh borders (both batches)
// ---------------------------------------------------------------------------
__global__ __launch_bounds__(256) void prep_kernel(
    const float* __restrict__ x, const float* __restrict__ feat,
    const float* __restrict__ wdcn, const float* __restrict__ wom,
    unsigned short* __restrict__ xTh,
    unsigned short* __restrict__ fh,
    unsigned short* __restrict__ whi,
    unsigned short* __restrict__ wohi)
{
    const int bid = blockIdx.x;
    const int tid = threadIdx.x;

    if (bid < 4096) {
        const bool isx = bid < 2048;
        const int lb = isx ? bid : bid - 2048;
        const int b  = lb >> 10;
        const int r  = lb & 1023;
        const int pt = r >> 3;       // 128 px tiles of 32
        const int ct = r & 7;        // 8 ch tiles of 32
        __shared__ float t[32][33];
        const int tx = tid & 31, ty = tid >> 5;
        const float* src = isx ? x : feat;
        const float* sb = src + ((size_t)b * 256 + ct * 32) * HWPIX + pt * 32;
#pragma unroll
        for (int i = ty; i < 32; i += 8)
            t[i][tx] = sb[(size_t)i * HWPIX + tx];
        __syncthreads();
        // one 8B store per thread: 1 px x 4 ch (t reads are 2-way = free)
        const int px = tid >> 3;
        const int c4 = (tid & 7) << 2;
        float a0 = t[c4][px], a1 = t[c4 + 1][px];
        float a2 = t[c4 + 2][px], a3 = t[c4 + 3][px];
        uint2 rv = make_uint2(cvtpk_bf16(a0, a1), cvtpk_bf16(a2, a3));
        if (isx) {
            *(uint2*)&xTh[((size_t)b * HWPIX + pt * 32 + px) * 256 + ct * 32 + c4] = rv;
        } else {
            int p = pt * 32 + px;
            int row = (p >> 6) + 1, col = (p & 63) + 1;
            *(uint2*)&fh[((size_t)b * PHW + row * PH + col) * 256 + ct * 32 + c4] = rv;
        }
    } else if (bid < 5248) {
        int g2 = (bid - 4096) * 256 + tid;     // 0..294911 (2 elems each)
        int e  = g2 * 2;
        int cc  = e & 31;
        int co  = (e >> 5) & 255;
        int kcb = e >> 13;
        int k   = kcb >> 3;
        int cb  = kcb & 7;
        const float* s = wdcn + ((size_t)co * 256 + cb * 32 + cc) * 9 + k;
        *(unsigned*)&whi[e] = cvtpk_bf16(s[0], s[9]);
    } else if (bid < 5536) {
        int gid = (bid - 5248) * 256 + tid;    // 0..73727
        int cc  = gid & 31;
        int co  = (gid >> 5) & 31;
        int kcb = gid >> 10;
        int k   = kcb >> 3;
        int cb  = kcb & 7;
        float w = 0.0f;
        if (co < 27) w = wom[(size_t)co * CKTOT + (cb * 32 + cc) * 9 + k];
        wohi[gid] = f2bf(w);
    } else {
        int idx = (bid - 5536) * 256 + tid;    // < 133120 = 2*260*256 exactly
        int b = idx / 66560;
        int r = idx - b * 66560;
        int pidx = r >> 8;                     // 0..259 border cells
        int c = r & 255;
        int row, col;
        if (pidx < 66)       { row = 0;           col = pidx; }
        else if (pidx < 132) { row = 65;          col = pidx - 66; }
        else if (pidx < 196) { row = pidx - 131;  col = 0; }
        else                 { row = pidx - 195;  col = 65; }
        fh[((size_t)b * PHW + row * PH + col) * 256 + c] = 0;
    }
}

// ---------------------------------------------------------------------------
// dcn v17: v15/v16 pipeline + cog split for 2 blocks/CU.
// Block = (y, xh, cog, b): 32-px tile, 128 co, FULL K. Grid (128,2,2) = 512
// blocks = 2/CU (LDS 54KB x2 = 108KB <= 160KB; launch_bounds(512,4) caps
// VGPR at 128). Phase A + staging duplicated per cog pair (proven
// off-critical-path in round 1); main GEMM not duplicated. Pipeline:
// reg-prefetch gathers, V double-buffer, ONE barrier per cb, packed-f32
// interp, plain stores (full K -> no atomics).
// ---------------------------------------------------------------------------
__global__ __launch_bounds__(512, 4) void dcn_fused_kernel(
    const unsigned short* __restrict__ xTh,    // [2][4096][256] bf16
    const unsigned short* __restrict__ fh,     // [2][4356][256] bf16
    const unsigned short* __restrict__ whi,    // [72][256][32] bf16
    const unsigned short* __restrict__ wohi,   // [72][32][32] bf16
    const float* __restrict__ bom,             // [27]
    const float* __restrict__ bdcn,            // [256]
    float* __restrict__ out)                   // [2][256][4096]
{
    const int tid = threadIdx.x;
    const int y   = blockIdx.x >> 1;           // 0..63
    const int xh  = blockIdx.x & 1;            // 0..1 (32-px halves)
    const int cog = blockIdx.y;                // 0..1 (co halves)
    const int b   = blockIdx.z;

    __shared__ __align__(16) char smem[2 * VBUF * 2 + 288 * 16 + 288 * 16];
    float (*red)[32][32]   = (float (*)[32][32])smem;          // Phase A only
    unsigned short* V      = (unsigned short*)smem;            // Phase B dbuf
    float4* s_wt           = (float4*)(smem + 2 * VBUF * 2);
    int4*   s_ix           = (int4*)(smem + 2 * VBUF * 2 + 288 * 16);

    const int wv   = tid >> 6;
    const int lane = tid & 63;
    const int l15  = lane & 15;
    const int q    = lane >> 4;

    // ---- Phase A: offset/mask conv (27 x 32px), K-split across 8 waves ----
    {
        float4v aco[2][2];
#pragma unroll
        for (int t = 0; t < 2; ++t)
#pragma unroll
            for (int p = 0; p < 2; ++p) aco[t][p] = (float4v)0.0f;

        const unsigned short* fhb = fh + (size_t)b * PHW * 256;
#pragma unroll 3
        for (int i = 0; i < 9; ++i) {
            int kcb = wv * 9 + i;              // 72 kcb over 8 waves
            int k  = kcb >> 3;
            int cb = kcb & 7;
            size_t s = ((size_t)((y + k / 3) * PH + xh * 32 + (k % 3))) * 256
                     + cb * 32 + q * 8;
            short8 bh0 = *(const short8*)(fhb + s + (size_t)l15 * 256);
            short8 bh1 = *(const short8*)(fhb + s + (size_t)(16 + l15) * 256);
            short8 ah0 = *(const short8*)(wohi + ((size_t)kcb * 32 + l15) * 32 + q * 8);
            short8 ah1 = *(const short8*)(wohi + ((size_t)kcb * 32 + 16 + l15) * 32 + q * 8);
            aco[0][0] = __builtin_amdgcn_mfma_f32_16x16x32_bf16(ah0, bh0, aco[0][0], 0, 0, 0);
            aco[0][1] = __builtin_amdgcn_mfma_f32_16x16x32_bf16(ah0, bh1, aco[0][1], 0, 0, 0);
            aco[1][0] = __builtin_amdgcn_mfma_f32_16x16x32_bf16(ah1, bh0, aco[1][0], 0, 0, 0);
            aco[1][1] = __builtin_amdgcn_mfma_f32_16x16x32_bf16(ah1, bh1, aco[1][1], 0, 0, 0);
        }
#pragma unroll
        for (int t = 0; t < 2; ++t)
#pragma unroll
            for (int p = 0; p < 2; ++p)
#pragma unroll
                for (int r = 0; r < 4; ++r)
                    red[wv][t * 16 + q * 4 + r][p * 16 + l15] = aco[t][p][r];
    }
    __syncthreads();

    if (tid < 288) {
        int k   = tid >> 5;
        int pxl = tid & 31;
        float dy = bom[2 * k], dx = bom[2 * k + 1], mm = bom[18 + k];
#pragma unroll
        for (int g = 0; g < 8; ++g) {
            dy += red[g][2 * k][pxl];
            dx += red[g][2 * k + 1][pxl];
            mm += red[g][18 + k][pxl];
        }
        int xx = xh * 32 + pxl;
        float ys = (float)(y  - 1 + (k / 3)) + dy;
        float xs = (float)(xx - 1 + (k % 3)) + dx;
        float y0f = floorf(ys), x0f = floorf(xs);
        int y0 = (int)y0f, x0 = (int)x0f;
        float ly = ys - y0f, lx = xs - x0f;
        float m  = 1.0f / (1.0f + expf(-mm));
        bool yv0 = ((unsigned)y0 < 64u), yv1 = ((unsigned)(y0 + 1) < 64u);
        bool xv0 = ((unsigned)x0 < 64u), xv1 = ((unsigned)(x0 + 1) < 64u);
        int i00 = (y0 * 64 + x0) << 8;         // element offset * 256 ch
        float4 wt;
        int4 ix;
        wt.x = (yv0 && xv0) ? (1.0f - ly) * (1.0f - lx) * m : 0.0f;
        wt.y = (yv0 && xv1) ? (1.0f - ly) * lx * m          : 0.0f;
        wt.z = (yv1 && xv0) ? ly * (1.0f - lx) * m          : 0.0f;
        wt.w = (yv1 && xv1) ? ly * lx * m                   : 0.0f;
        ix.x = (yv0 && xv0) ? i00          : 0;
        ix.y = (yv0 && xv1) ? i00 + 256    : 0;
        ix.z = (yv1 && xv0) ? i00 + 16384  : 0;
        ix.w = (yv1 && xv1) ? i00 + 16640  : 0;
        s_wt[tid] = wt;                        // tid == k*32 + pxl == cidx
        s_ix[tid] = ix;
    }
    __syncthreads();                           // red dead from here; V alive

    // ---- Phase B: pipelined DCN GEMM over 8 cb; this block does 128 co ----
    const int w = tid >> 6;                    // wave -> co = cog*128 + w*16

    const int cg2  = tid & 3;                  // 8-ch group
    const int spx  = (tid >> 2) & 31;
    const int tapg = tid >> 7;                 // taps k = tapg + 4*j (wave-uniform)

    float4v acc[2];
    acc[0] = (float4v)0.0f;
    acc[1] = (float4v)0.0f;

    const unsigned short* xc0 = xTh + ((size_t)b << 12) * 256 + cg2 * 8;

    uint4 pf[3][4];                            // prefetched corners (48 VGPR)

    auto gload = [&](int cb) {
        const unsigned short* xc = xc0 + cb * 32;
#pragma unroll
        for (int j = 0; j < 3; ++j) {
            int k = tapg + 4 * j;
            if (k > 8) continue;               // wave-uniform branch
            int4 ix = s_ix[k * 32 + spx];
            pf[j][0] = *(const uint4*)(xc + ix.x);
            pf[j][1] = *(const uint4*)(xc + ix.y);
            pf[j][2] = *(const uint4*)(xc + ix.z);
            pf[j][3] = *(const uint4*)(xc + ix.w);
        }
    };
    auto interp = [&](int buf) {
#pragma unroll
        for (int j = 0; j < 3; ++j) {
            int k = tapg + 4 * j;
            if (k > 8) continue;
            int cidx = k * 32 + spx;
            float4 wt = s_wt[cidx];
            const unsigned* u00 = (const unsigned*)&pf[j][0];
            const unsigned* u01 = (const unsigned*)&pf[j][1];
            const unsigned* u10 = (const unsigned*)&pf[j][2];
            const unsigned* u11 = (const unsigned*)&pf[j][3];
            unsigned hv[4];
#pragma unroll
            for (int jj = 0; jj < 4; ++jj) {
                float2v s = unpk(u00[jj]) * wt.x;
                s += unpk(u01[jj]) * wt.y;
                s += unpk(u10[jj]) * wt.z;
                s += unpk(u11[jj]) * wt.w;
                hv[jj] = cvtpk_bf16(s.x, s.y);
            }
            *(uint4*)&V[buf * VBUF + cidx * VSTR + cg2 * 8]
                = make_uint4(hv[0], hv[1], hv[2], hv[3]);
        }
    };

    gload(0);                                  // prologue prefetch

    for (int cb = 0; cb < 8; ++cb) {
        const int buf = cb & 1;
        interp(buf);                           // consume pf -> V[buf]
        if (cb < 7) gload(cb + 1);             // issue next-tile gathers
        __syncthreads();                       // V[buf] ready for all waves

        // ---- 9 MFMA chunks on this cb: 1 A-load + 2 ds + 2 MFMA each ----
#pragma unroll 3
        for (int k = 0; k < 9; ++k) {
            const int kcb = k * 8 + cb;
            size_t base = ((size_t)kcb * 256 + cog * 128 + w * 16 + l15) * 32 + q * 8;
            short8 ah  = *(const short8*)(whi + base);
            short8 bh0 = *(const short8*)&V[buf * VBUF + (k * 32 + l15) * VSTR + q * 8];
            short8 bh1 = *(const short8*)&V[buf * VBUF + (k * 32 + 16 + l15) * VSTR + q * 8];
            acc[0] = __builtin_amdgcn_mfma_f32_16x16x32_bf16(ah, bh0, acc[0], 0, 0, 0);
            acc[1] = __builtin_amdgcn_mfma_f32_16x16x32_bf16(ah, bh1, acc[1], 0, 0, 0);
        }
        // no second barrier: next iter writes V[buf^1]
    }

    // ---- epilogue: plain stores (full K in this block) + bias ----
#pragma unroll
    for (int r = 0; r < 4; ++r) {
        int co = cog * 128 + w * 16 + q * 4 + r;
        float bias = bdcn[co];
#pragma unroll
        for (int p = 0; p < 2; ++p) {
            int px = xh * 32 + p * 16 + l15;
            out[(((size_t)b * 256 + co) << 12) + y * 64 + px]
                = acc[p][r] + bias;
        }
    }
}

// ---------------------------------------------------------------------------
extern "C" void kernel_launch(void* const* d_in, const int* in_sizes, int n_in,
                              void* d_out, int out_size, void* d_ws, size_t ws_size,
                              hipStream_t stream)
{
    const float* x    = (const float*)d_in[0];
    const float* feat = (const float*)d_in[1];
    const float* wom  = (const float*)d_in[2];
    const float* bom  = (const float*)d_in[3];
    const float* wdcn = (const float*)d_in[4];
    const float* bdcn = (const float*)d_in[5];
    float* out = (float*)d_out;

    // workspace layout (all 16B-aligned)
    unsigned short* whi  = (unsigned short*)d_ws;                // 589824 sh
    unsigned short* wohi = whi + (size_t)CKTOT * 256;            // 73728 sh
    unsigned short* xTh  = wohi + 73728;                         // 2*4096*256
    unsigned short* fh   = xTh + (size_t)2 * HWPIX * 256;        // 2*4356*256

    prep_kernel<<<6056, 256, 0, stream>>>(x, feat, wdcn, wom, xTh, fh,
                                          whi, wohi);

    dim3 grid(128, 2, 2);
    dcn_fused_kernel<<<grid, 512, 0, stream>>>(xTh, fh, whi, wohi,
                                               bom, bdcn, out);
}

// Round 9
// 119.956 us; speedup vs baseline: 1.0133x; 1.0133x over previous
//
#include <hip/hip_runtime.h>
#include <math.h>

#define HWPIX 4096
#define CKTOT 2304
#define VSTR  40            // V row stride in shorts (80 B)
#define PH    66            // padded feat spatial dim
#define PHW   4356          // 66*66
#define VBUF  (288 * VSTR)  // one V buffer in shorts (23040 B)

typedef __attribute__((ext_vector_type(8))) short short8;
typedef __attribute__((ext_vector_type(2))) float float2v;
typedef __attribute__((ext_vector_type(4))) float float4v;

__device__ __forceinline__ unsigned short f2bf(float f) {
    unsigned u = __float_as_uint(f);
    unsigned r = (u + 0x7FFFu + ((u >> 16) & 1u)) >> 16;   // RNE
    return (unsigned short)r;
}
__device__ __forceinline__ float bf2f(unsigned short h) {
    return __uint_as_float(((unsigned)h) << 16);
}
// hardware packed f32->2xbf16 (RNE), lo=a, hi=b — no builtin on gfx950
__device__ __forceinline__ unsigned cvtpk_bf16(float a, float b) {
    unsigned r;
    asm("v_cvt_pk_bf16_f32 %0, %1, %2" : "=v"(r) : "v"(a), "v"(b));
    return r;
}
// unpack u32 (2x bf16) -> float2 {lo, hi}
__device__ __forceinline__ float2v unpk(unsigned u) {
    float2v r;
    r.x = __uint_as_float(u << 16);
    r.y = __uint_as_float(u & 0xffff0000u);
    return r;
}

// ---------------------------------------------------------------------------
// prep (unchanged — verified 3 rounds): blockIdx regions:
//   [0,4096)      x -> xTh / feat -> fh transposes (8B vectorized bf16 stores)
//   [4096,5248)   wpack   (w_dcn -> whi, 2 elems/thread, 4B stores)
//   [5248,5536)   wpack_om(w_offset_mask -> wohi, M=32 padded)
//   [5536,6056)   zero fh borders (both batches)
// ---------------------------------------------------------------------------
__global__ __launch_bounds__(256) void prep_kernel(
    const float* __restrict__ x, const float* __restrict__ feat,
    const float* __restrict__ wdcn, const float* __restrict__ wom,
    unsigned short* __restrict__ xTh,
    unsigned short* __restrict__ fh,
    unsigned short* __restrict__ whi,
    unsigned short* __restrict__ wohi)
{
    const int bid = blockIdx.x;
    const int tid = threadIdx.x;

    if (bid < 4096) {
        const bool isx = bid < 2048;
        const int lb = isx ? bid : bid - 2048;
        const int b  = lb >> 10;
        const int r  = lb & 1023;
        const int pt = r >> 3;       // 128 px tiles of 32
        const int ct = r & 7;        // 8 ch tiles of 32
        __shared__ float t[32][33];
        const int tx = tid & 31, ty = tid >> 5;
        const float* src = isx ? x : feat;
        const float* sb = src + ((size_t)b * 256 + ct * 32) * HWPIX + pt * 32;
#pragma unroll
        for (int i = ty; i < 32; i += 8)
            t[i][tx] = sb[(size_t)i * HWPIX + tx];
        __syncthreads();
        // one 8B store per thread: 1 px x 4 ch (t reads are 2-way = free)
        const int px = tid >> 3;
        const int c4 = (tid & 7) << 2;
        float a0 = t[c4][px], a1 = t[c4 + 1][px];
        float a2 = t[c4 + 2][px], a3 = t[c4 + 3][px];
        uint2 rv = make_uint2(cvtpk_bf16(a0, a1), cvtpk_bf16(a2, a3));
        if (isx) {
            *(uint2*)&xTh[((size_t)b * HWPIX + pt * 32 + px) * 256 + ct * 32 + c4] = rv;
        } else {
            int p = pt * 32 + px;
            int row = (p >> 6) + 1, col = (p & 63) + 1;
            *(uint2*)&fh[((size_t)b * PHW + row * PH + col) * 256 + ct * 32 + c4] = rv;
        }
    } else if (bid < 5248) {
        int g2 = (bid - 4096) * 256 + tid;     // 0..294911 (2 elems each)
        int e  = g2 * 2;
        int cc  = e & 31;
        int co  = (e >> 5) & 255;
        int kcb = e >> 13;
        int k   = kcb >> 3;
        int cb  = kcb & 7;
        const float* s = wdcn + ((size_t)co * 256 + cb * 32 + cc) * 9 + k;
        *(unsigned*)&whi[e] = cvtpk_bf16(s[0], s[9]);
    } else if (bid < 5536) {
        int gid = (bid - 5248) * 256 + tid;    // 0..73727
        int cc  = gid & 31;
        int co  = (gid >> 5) & 31;
        int kcb = gid >> 10;
        int k   = kcb >> 3;
        int cb  = kcb & 7;
        float w = 0.0f;
        if (co < 27) w = wom[(size_t)co * CKTOT + (cb * 32 + cc) * 9 + k];
        wohi[gid] = f2bf(w);
    } else {
        int idx = (bid - 5536) * 256 + tid;    // < 133120 = 2*260*256 exactly
        int b = idx / 66560;
        int r = idx - b * 66560;
        int pidx = r >> 8;                     // 0..259 border cells
        int c = r & 255;
        int row, col;
        if (pidx < 66)       { row = 0;           col = pidx; }
        else if (pidx < 132) { row = 65;          col = pidx - 66; }
        else if (pidx < 196) { row = pidx - 131;  col = 0; }
        else                 { row = pidx - 195;  col = 65; }
        fh[((size_t)b * PHW + row * PH + col) * 256 + c] = 0;
    }
}

// ---------------------------------------------------------------------------
// dcn v18: EXACT v16 structure (best measured: 119.9 us) + bijective XCD
// chunk swizzle. Block = 32-px tile, ALL 256 co, FULL K; 512 thr (8 waves,
// each 32co x 32px, acc[2][2], 4 MFMA/chunk); reg-prefetch gathers, V dbuf,
// ONE barrier per cb, packed-f32 interp, rix/rwt register cache, plain
// stores. Grid = 256 (1D): orig%8 -> XCD (round-robin heuristic), so
// sb = (orig&7)*32 + orig>>3 gives each XCD 32 CONTIGUOUS blocks = 16
// consecutive y-rows of ONE batch. Working set per XCD-L2: whi 1.18MB +
// xTh slab ~0.6MB + fh slab ~0.3MB ~= 2.1MB < 4MB -> gathers become
// XCD-local L2 hits (r8 showed FETCH 20.3MB vs 9.6MB live = L2 thrash).
// ---------------------------------------------------------------------------
__global__ __launch_bounds__(512, 2) void dcn_fused_kernel(
    const unsigned short* __restrict__ xTh,    // [2][4096][256] bf16
    const unsigned short* __restrict__ fh,     // [2][4356][256] bf16
    const unsigned short* __restrict__ whi,    // [72][256][32] bf16
    const unsigned short* __restrict__ wohi,   // [72][32][32] bf16
    const float* __restrict__ bom,             // [27]
    const float* __restrict__ bdcn,            // [256]
    float* __restrict__ out)                   // [2][256][4096]
{
    const int tid  = threadIdx.x;
    // bijective XCD-chunk swizzle (256 % 8 == 0)
    const int orig = blockIdx.x;
    const int sb   = (orig & 7) * 32 + (orig >> 3);
    const int b    = sb >> 7;                  // 0..1
    const int yxh  = sb & 127;
    const int y    = yxh >> 1;                 // 0..63
    const int xh   = yxh & 1;                  // 0..1 (32-px halves)

    __shared__ __align__(16) char smem[2 * VBUF * 2 + 288 * 16 + 288 * 16];
    float (*red)[32][32]   = (float (*)[32][32])smem;          // Phase A only
    unsigned short* V      = (unsigned short*)smem;            // Phase B dbuf
    float4* s_wt           = (float4*)(smem + 2 * VBUF * 2);
    int4*   s_ix           = (int4*)(smem + 2 * VBUF * 2 + 288 * 16);

    const int wv   = tid >> 6;
    const int lane = tid & 63;
    const int l15  = lane & 15;
    const int q    = lane >> 4;

    // ---- Phase A: offset/mask conv (27 x 32px), K-split across 8 waves ----
    {
        float4v aco[2][2];
#pragma unroll
        for (int t = 0; t < 2; ++t)
#pragma unroll
            for (int p = 0; p < 2; ++p) aco[t][p] = (float4v)0.0f;

        const unsigned short* fhb = fh + (size_t)b * PHW * 256;
#pragma unroll 3
        for (int i = 0; i < 9; ++i) {
            int kcb = wv * 9 + i;              // 72 kcb over 8 waves
            int k  = kcb >> 3;
            int cb = kcb & 7;
            size_t s = ((size_t)((y + k / 3) * PH + xh * 32 + (k % 3))) * 256
                     + cb * 32 + q * 8;
            short8 bh0 = *(const short8*)(fhb + s + (size_t)l15 * 256);
            short8 bh1 = *(const short8*)(fhb + s + (size_t)(16 + l15) * 256);
            short8 ah0 = *(const short8*)(wohi + ((size_t)kcb * 32 + l15) * 32 + q * 8);
            short8 ah1 = *(const short8*)(wohi + ((size_t)kcb * 32 + 16 + l15) * 32 + q * 8);
            aco[0][0] = __builtin_amdgcn_mfma_f32_16x16x32_bf16(ah0, bh0, aco[0][0], 0, 0, 0);
            aco[0][1] = __builtin_amdgcn_mfma_f32_16x16x32_bf16(ah0, bh1, aco[0][1], 0, 0, 0);
            aco[1][0] = __builtin_amdgcn_mfma_f32_16x16x32_bf16(ah1, bh0, aco[1][0], 0, 0, 0);
            aco[1][1] = __builtin_amdgcn_mfma_f32_16x16x32_bf16(ah1, bh1, aco[1][1], 0, 0, 0);
        }
#pragma unroll
        for (int t = 0; t < 2; ++t)
#pragma unroll
            for (int p = 0; p < 2; ++p)
#pragma unroll
                for (int r = 0; r < 4; ++r)
                    red[wv][t * 16 + q * 4 + r][p * 16 + l15] = aco[t][p][r];
    }
    __syncthreads();

    if (tid < 288) {
        int k   = tid >> 5;
        int pxl = tid & 31;
        float dy = bom[2 * k], dx = bom[2 * k + 1], mm = bom[18 + k];
#pragma unroll
        for (int g = 0; g < 8; ++g) {
            dy += red[g][2 * k][pxl];
            dx += red[g][2 * k + 1][pxl];
            mm += red[g][18 + k][pxl];
        }
        int xx = xh * 32 + pxl;
        float ys = (float)(y  - 1 + (k / 3)) + dy;
        float xs = (float)(xx - 1 + (k % 3)) + dx;
        float y0f = floorf(ys), x0f = floorf(xs);
        int y0 = (int)y0f, x0 = (int)x0f;
        float ly = ys - y0f, lx = xs - x0f;
        float m  = 1.0f / (1.0f + expf(-mm));
        bool yv0 = ((unsigned)y0 < 64u), yv1 = ((unsigned)(y0 + 1) < 64u);
        bool xv0 = ((unsigned)x0 < 64u), xv1 = ((unsigned)(x0 + 1) < 64u);
        int i00 = (y0 * 64 + x0) << 8;         // element offset * 256 ch
        float4 wt;
        int4 ix;
        wt.x = (yv0 && xv0) ? (1.0f - ly) * (1.0f - lx) * m : 0.0f;
        wt.y = (yv0 && xv1) ? (1.0f - ly) * lx * m          : 0.0f;
        wt.z = (yv1 && xv0) ? ly * (1.0f - lx) * m          : 0.0f;
        wt.w = (yv1 && xv1) ? ly * lx * m                   : 0.0f;
        ix.x = (yv0 && xv0) ? i00          : 0;
        ix.y = (yv0 && xv1) ? i00 + 256    : 0;
        ix.z = (yv1 && xv0) ? i00 + 16384  : 0;
        ix.w = (yv1 && xv1) ? i00 + 16640  : 0;
        s_wt[tid] = wt;                        // tid == k*32 + pxl == cidx
        s_ix[tid] = ix;
    }
    __syncthreads();                           // red dead from here; V alive

    // ---- Phase B: pipelined DCN GEMM over 8 cb ----
    const int w = tid >> 6;                    // wave -> co base w*32

    // staging map: cg = tid&3 (8 ch), spx = (tid>>2)&31, tapg = tid>>7 (0..3)
    const int cg   = tid & 3;
    const int spx  = (tid >> 2) & 31;
    const int tapg = tid >> 7;                 // taps k = tapg + 4*j (wave-uniform)

    // cb-invariant per-thread gather state cached in registers
    int4   rix[3];
    float4 rwt[3];
#pragma unroll
    for (int j = 0; j < 3; ++j) {
        int k = tapg + 4 * j;
        if (k > 8) continue;                   // wave-uniform
        rix[j] = s_ix[k * 32 + spx];
        rwt[j] = s_wt[k * 32 + spx];
    }

    float4v acc[2][2];
#pragma unroll
    for (int t = 0; t < 2; ++t)
#pragma unroll
        for (int p = 0; p < 2; ++p) acc[t][p] = (float4v)0.0f;

    const unsigned short* xc0 = xTh + ((size_t)b << 12) * 256 + cg * 8;

    uint4 pf[3][4];                            // prefetched corners (48 VGPR)

    auto gload = [&](int cb) {
        const unsigned short* xc = xc0 + cb * 32;
#pragma unroll
        for (int j = 0; j < 3; ++j) {
            int k = tapg + 4 * j;
            if (k > 8) continue;               // wave-uniform branch
            int4 ix = rix[j];
            pf[j][0] = *(const uint4*)(xc + ix.x);
            pf[j][1] = *(const uint4*)(xc + ix.y);
            pf[j][2] = *(const uint4*)(xc + ix.z);
            pf[j][3] = *(const uint4*)(xc + ix.w);
        }
    };
    auto interp = [&](int buf) {
#pragma unroll
        for (int j = 0; j < 3; ++j) {
            int k = tapg + 4 * j;
            if (k > 8) continue;
            int cidx = k * 32 + spx;
            float4 wt = rwt[j];
            const unsigned* u00 = (const unsigned*)&pf[j][0];
            const unsigned* u01 = (const unsigned*)&pf[j][1];
            const unsigned* u10 = (const unsigned*)&pf[j][2];
            const unsigned* u11 = (const unsigned*)&pf[j][3];
            unsigned hv[4];
#pragma unroll
            for (int jj = 0; jj < 4; ++jj) {
                float2v s = unpk(u00[jj]) * wt.x;
                s += unpk(u01[jj]) * wt.y;
                s += unpk(u10[jj]) * wt.z;
                s += unpk(u11[jj]) * wt.w;
                hv[jj] = cvtpk_bf16(s.x, s.y);
            }
            *(uint4*)&V[buf * VBUF + cidx * VSTR + cg * 8]
                = make_uint4(hv[0], hv[1], hv[2], hv[3]);
        }
    };

    gload(0);                                  // prologue prefetch

    for (int cb = 0; cb < 8; ++cb) {
        const int buf = cb & 1;
        interp(buf);                           // consume pf -> V[buf]
        if (cb < 7) gload(cb + 1);             // issue next-tile gathers
        __syncthreads();                       // V[buf] ready for all waves

        // ---- 9 MFMA chunks on this cb: 2 A-loads + 2 ds + 4 MFMA each ----
#pragma unroll 3
        for (int k = 0; k < 9; ++k) {
            const int kcb = k * 8 + cb;
            size_t base = ((size_t)kcb * 256 + w * 32 + l15) * 32 + q * 8;
            short8 ah0 = *(const short8*)(whi + base);
            short8 ah1 = *(const short8*)(whi + base + 16 * 32);
            short8 bh0 = *(const short8*)&V[buf * VBUF + (k * 32 + l15) * VSTR + q * 8];
            short8 bh1 = *(const short8*)&V[buf * VBUF + (k * 32 + 16 + l15) * VSTR + q * 8];
            acc[0][0] = __builtin_amdgcn_mfma_f32_16x16x32_bf16(ah0, bh0, acc[0][0], 0, 0, 0);
            acc[0][1] = __builtin_amdgcn_mfma_f32_16x16x32_bf16(ah0, bh1, acc[0][1], 0, 0, 0);
            acc[1][0] = __builtin_amdgcn_mfma_f32_16x16x32_bf16(ah1, bh0, acc[1][0], 0, 0, 0);
            acc[1][1] = __builtin_amdgcn_mfma_f32_16x16x32_bf16(ah1, bh1, acc[1][1], 0, 0, 0);
        }
        // no second barrier: next iter writes V[buf^1]
    }

    // ---- epilogue: plain stores (full K in this block) + bias ----
#pragma unroll
    for (int t = 0; t < 2; ++t) {
#pragma unroll
        for (int r = 0; r < 4; ++r) {
            int co = w * 32 + t * 16 + q * 4 + r;
            float bias = bdcn[co];
#pragma unroll
            for (int p = 0; p < 2; ++p) {
                int px = xh * 32 + p * 16 + l15;
                out[(((size_t)b * 256 + co) << 12) + y * 64 + px]
                    = acc[t][p][r] + bias;
            }
        }
    }
}

// ---------------------------------------------------------------------------
extern "C" void kernel_launch(void* const* d_in, const int* in_sizes, int n_in,
                              void* d_out, int out_size, void* d_ws, size_t ws_size,
                              hipStream_t stream)
{
    const float* x    = (const float*)d_in[0];
    const float* feat = (const float*)d_in[1];
    const float* wom  = (const float*)d_in[2];
    const float* bom  = (const float*)d_in[3];
    const float* wdcn = (const float*)d_in[4];
    const float* bdcn = (const float*)d_in[5];
    float* out = (float*)d_out;

    // workspace layout (all 16B-aligned)
    unsigned short* whi  = (unsigned short*)d_ws;                // 589824 sh
    unsigned short* wohi = whi + (size_t)CKTOT * 256;            // 73728 sh
    unsigned short* xTh  = wohi + 73728;                         // 2*4096*256
    unsigned short* fh   = xTh + (size_t)2 * HWPIX * 256;        // 2*4356*256

    prep_kernel<<<6056, 256, 0, stream>>>(x, feat, wdcn, wom, xTh, fh,
                                          whi, wohi);

    dcn_fused_kernel<<<256, 512, 0, stream>>>(xTh, fh, whi, wohi,
                                              bom, bdcn, out);
}

// Round 10
// 109.947 us; speedup vs baseline: 1.1055x; 1.0910x over previous
//
#include <hip/hip_runtime.h>
#include <math.h>

#define HWPIX 4096
#define CKTOT 2304
#define VSTR  40            // V row stride in shorts (80 B)
#define PH    66            // padded feat spatial dim
#define PHW   4356          // 66*66
#define VBUF  (288 * VSTR)  // one V buffer in shorts (23040 B)

typedef __attribute__((ext_vector_type(8))) short short8;
typedef __attribute__((ext_vector_type(2))) float float2v;
typedef __attribute__((ext_vector_type(4))) float float4v;

__device__ __forceinline__ unsigned short f2bf(float f) {
    unsigned u = __float_as_uint(f);
    unsigned r = (u + 0x7FFFu + ((u >> 16) & 1u)) >> 16;   // RNE
    return (unsigned short)r;
}
__device__ __forceinline__ float bf2f(unsigned short h) {
    return __uint_as_float(((unsigned)h) << 16);
}
// hardware packed f32->2xbf16 (RNE), lo=a, hi=b — no builtin on gfx950
__device__ __forceinline__ unsigned cvtpk_bf16(float a, float b) {
    unsigned r;
    asm("v_cvt_pk_bf16_f32 %0, %1, %2" : "=v"(r) : "v"(a), "v"(b));
    return r;
}
// unpack u32 (2x bf16) -> float2 {lo, hi}
__device__ __forceinline__ float2v unpk(unsigned u) {
    float2v r;
    r.x = __uint_as_float(u << 16);
    r.y = __uint_as_float(u & 0xffff0000u);
    return r;
}

// ---------------------------------------------------------------------------
// prep (unchanged — verified 4 rounds): blockIdx regions:
//   [0,4096)      x -> xTh / feat -> fh transposes (8B vectorized bf16 stores)
//   [4096,5248)   wpack   (w_dcn -> whi, 2 elems/thread, 4B stores)
//   [5248,5536)   wpack_om(w_offset_mask -> wohi, M=32 padded)
//   [5536,6056)   zero fh borders (both batches)
// ---------------------------------------------------------------------------
__global__ __launch_bounds__(256) void prep_kernel(
    const float* __restrict__ x, const float* __restrict__ feat,
    const float* __restrict__ wdcn, const float* __restrict__ wom,
    unsigned short* __restrict__ xTh,
    unsigned short* __restrict__ fh,
    unsigned short* __restrict__ whi,
    unsigned short* __restrict__ wohi)
{
    const int bid = blockIdx.x;
    const int tid = threadIdx.x;

    if (bid < 4096) {
        const bool isx = bid < 2048;
        const int lb = isx ? bid : bid - 2048;
        const int b  = lb >> 10;
        const int r  = lb & 1023;
        const int pt = r >> 3;       // 128 px tiles of 32
        const int ct = r & 7;        // 8 ch tiles of 32
        __shared__ float t[32][33];
        const int tx = tid & 31, ty = tid >> 5;
        const float* src = isx ? x : feat;
        const float* sb = src + ((size_t)b * 256 + ct * 32) * HWPIX + pt * 32;
#pragma unroll
        for (int i = ty; i < 32; i += 8)
            t[i][tx] = sb[(size_t)i * HWPIX + tx];
        __syncthreads();
        // one 8B store per thread: 1 px x 4 ch (t reads are 2-way = free)
        const int px = tid >> 3;
        const int c4 = (tid & 7) << 2;
        float a0 = t[c4][px], a1 = t[c4 + 1][px];
        float a2 = t[c4 + 2][px], a3 = t[c4 + 3][px];
        uint2 rv = make_uint2(cvtpk_bf16(a0, a1), cvtpk_bf16(a2, a3));
        if (isx) {
            *(uint2*)&xTh[((size_t)b * HWPIX + pt * 32 + px) * 256 + ct * 32 + c4] = rv;
        } else {
            int p = pt * 32 + px;
            int row = (p >> 6) + 1, col = (p & 63) + 1;
            *(uint2*)&fh[((size_t)b * PHW + row * PH + col) * 256 + ct * 32 + c4] = rv;
        }
    } else if (bid < 5248) {
        int g2 = (bid - 4096) * 256 + tid;     // 0..294911 (2 elems each)
        int e  = g2 * 2;
        int cc  = e & 31;
        int co  = (e >> 5) & 255;
        int kcb = e >> 13;
        int k   = kcb >> 3;
        int cb  = kcb & 7;
        const float* s = wdcn + ((size_t)co * 256 + cb * 32 + cc) * 9 + k;
        *(unsigned*)&whi[e] = cvtpk_bf16(s[0], s[9]);
    } else if (bid < 5536) {
        int gid = (bid - 5248) * 256 + tid;    // 0..73727
        int cc  = gid & 31;
        int co  = (gid >> 5) & 31;
        int kcb = gid >> 10;
        int k   = kcb >> 3;
        int cb  = kcb & 7;
        float w = 0.0f;
        if (co < 27) w = wom[(size_t)co * CKTOT + (cb * 32 + cc) * 9 + k];
        wohi[gid] = f2bf(w);
    } else {
        int idx = (bid - 5536) * 256 + tid;    // < 133120 = 2*260*256 exactly
        int b = idx / 66560;
        int r = idx - b * 66560;
        int pidx = r >> 8;                     // 0..259 border cells
        int c = r & 255;
        int row, col;
        if (pidx < 66)       { row = 0;           col = pidx; }
        else if (pidx < 132) { row = 65;          col = pidx - 66; }
        else if (pidx < 196) { row = pidx - 131;  col = 0; }
        else                 { row = pidx - 195;  col = 65; }
        fh[((size_t)b * PHW + row * PH + col) * 256 + c] = 0;
    }
}

// ---------------------------------------------------------------------------
// dcn v19: v16 structure (best measured) + whole-k-loop whi REGISTER
// prefetch issued BEFORE the barrier. The MFMA phase had 18 global whi
// loads per wave whose latency landed after the barrier (lockstep stall,
// 1 block/CU). whi addresses are static -> load ah0[9]/ah1[9] (72 VGPR) at
// the top of each cb iteration; latency hides under interp + gload issue +
// barrier. Post-barrier phase is pure ds_read+MFMA. Counted vmcnt keeps
// the cb+1 gathers in flight (no drain). launch_bounds(512,2): VGPR cap
// 256, 8 waves/CU. No XCD swizzle (proven null, r9).
// ---------------------------------------------------------------------------
__global__ __launch_bounds__(512, 2) void dcn_fused_kernel(
    const unsigned short* __restrict__ xTh,    // [2][4096][256] bf16
    const unsigned short* __restrict__ fh,     // [2][4356][256] bf16
    const unsigned short* __restrict__ whi,    // [72][256][32] bf16
    const unsigned short* __restrict__ wohi,   // [72][32][32] bf16
    const float* __restrict__ bom,             // [27]
    const float* __restrict__ bdcn,            // [256]
    float* __restrict__ out)                   // [2][256][4096]
{
    const int tid = threadIdx.x;
    const int y   = blockIdx.x >> 1;           // 0..63
    const int xh  = blockIdx.x & 1;            // 0..1 (32-px halves)
    const int b   = blockIdx.y;

    __shared__ __align__(16) char smem[2 * VBUF * 2 + 288 * 16 + 288 * 16];
    float (*red)[32][32]   = (float (*)[32][32])smem;          // Phase A only
    unsigned short* V      = (unsigned short*)smem;            // Phase B dbuf
    float4* s_wt           = (float4*)(smem + 2 * VBUF * 2);
    int4*   s_ix           = (int4*)(smem + 2 * VBUF * 2 + 288 * 16);

    const int wv   = tid >> 6;
    const int lane = tid & 63;
    const int l15  = lane & 15;
    const int q    = lane >> 4;

    // ---- Phase A: offset/mask conv (27 x 32px), K-split across 8 waves ----
    {
        float4v aco[2][2];
#pragma unroll
        for (int t = 0; t < 2; ++t)
#pragma unroll
            for (int p = 0; p < 2; ++p) aco[t][p] = (float4v)0.0f;

        const unsigned short* fhb = fh + (size_t)b * PHW * 256;
#pragma unroll 3
        for (int i = 0; i < 9; ++i) {
            int kcb = wv * 9 + i;              // 72 kcb over 8 waves
            int k  = kcb >> 3;
            int cb = kcb & 7;
            size_t s = ((size_t)((y + k / 3) * PH + xh * 32 + (k % 3))) * 256
                     + cb * 32 + q * 8;
            short8 bh0 = *(const short8*)(fhb + s + (size_t)l15 * 256);
            short8 bh1 = *(const short8*)(fhb + s + (size_t)(16 + l15) * 256);
            short8 ah0 = *(const short8*)(wohi + ((size_t)kcb * 32 + l15) * 32 + q * 8);
            short8 ah1 = *(const short8*)(wohi + ((size_t)kcb * 32 + 16 + l15) * 32 + q * 8);
            aco[0][0] = __builtin_amdgcn_mfma_f32_16x16x32_bf16(ah0, bh0, aco[0][0], 0, 0, 0);
            aco[0][1] = __builtin_amdgcn_mfma_f32_16x16x32_bf16(ah0, bh1, aco[0][1], 0, 0, 0);
            aco[1][0] = __builtin_amdgcn_mfma_f32_16x16x32_bf16(ah1, bh0, aco[1][0], 0, 0, 0);
            aco[1][1] = __builtin_amdgcn_mfma_f32_16x16x32_bf16(ah1, bh1, aco[1][1], 0, 0, 0);
        }
#pragma unroll
        for (int t = 0; t < 2; ++t)
#pragma unroll
            for (int p = 0; p < 2; ++p)
#pragma unroll
                for (int r = 0; r < 4; ++r)
                    red[wv][t * 16 + q * 4 + r][p * 16 + l15] = aco[t][p][r];
    }
    __syncthreads();

    if (tid < 288) {
        int k   = tid >> 5;
        int pxl = tid & 31;
        float dy = bom[2 * k], dx = bom[2 * k + 1], mm = bom[18 + k];
#pragma unroll
        for (int g = 0; g < 8; ++g) {
            dy += red[g][2 * k][pxl];
            dx += red[g][2 * k + 1][pxl];
            mm += red[g][18 + k][pxl];
        }
        int xx = xh * 32 + pxl;
        float ys = (float)(y  - 1 + (k / 3)) + dy;
        float xs = (float)(xx - 1 + (k % 3)) + dx;
        float y0f = floorf(ys), x0f = floorf(xs);
        int y0 = (int)y0f, x0 = (int)x0f;
        float ly = ys - y0f, lx = xs - x0f;
        float m  = 1.0f / (1.0f + expf(-mm));
        bool yv0 = ((unsigned)y0 < 64u), yv1 = ((unsigned)(y0 + 1) < 64u);
        bool xv0 = ((unsigned)x0 < 64u), xv1 = ((unsigned)(x0 + 1) < 64u);
        int i00 = (y0 * 64 + x0) << 8;         // element offset * 256 ch
        float4 wt;
        int4 ix;
        wt.x = (yv0 && xv0) ? (1.0f - ly) * (1.0f - lx) * m : 0.0f;
        wt.y = (yv0 && xv1) ? (1.0f - ly) * lx * m          : 0.0f;
        wt.z = (yv1 && xv0) ? ly * (1.0f - lx) * m          : 0.0f;
        wt.w = (yv1 && xv1) ? ly * lx * m                   : 0.0f;
        ix.x = (yv0 && xv0) ? i00          : 0;
        ix.y = (yv0 && xv1) ? i00 + 256    : 0;
        ix.z = (yv1 && xv0) ? i00 + 16384  : 0;
        ix.w = (yv1 && xv1) ? i00 + 16640  : 0;
        s_wt[tid] = wt;                        // tid == k*32 + pxl == cidx
        s_ix[tid] = ix;
    }
    __syncthreads();                           // red dead from here; V alive

    // ---- Phase B: pipelined DCN GEMM over 8 cb ----
    const int w = tid >> 6;                    // wave -> co base w*32

    // staging map: cg = tid&3 (8 ch), spx = (tid>>2)&31, tapg = tid>>7 (0..3)
    const int cg   = tid & 3;
    const int spx  = (tid >> 2) & 31;
    const int tapg = tid >> 7;                 // taps k = tapg + 4*j (wave-uniform)

    // cb-invariant per-thread gather state cached in registers
    int4   rix[3];
    float4 rwt[3];
#pragma unroll
    for (int j = 0; j < 3; ++j) {
        int k = tapg + 4 * j;
        if (k > 8) continue;                   // wave-uniform
        rix[j] = s_ix[k * 32 + spx];
        rwt[j] = s_wt[k * 32 + spx];
    }

    float4v acc[2][2];
#pragma unroll
    for (int t = 0; t < 2; ++t)
#pragma unroll
        for (int p = 0; p < 2; ++p) acc[t][p] = (float4v)0.0f;

    const unsigned short* xc0 = xTh + ((size_t)b << 12) * 256 + cg * 8;

    uint4 pf[3][4];                            // prefetched corners (48 VGPR)

    auto gload = [&](int cb) {
        const unsigned short* xc = xc0 + cb * 32;
#pragma unroll
        for (int j = 0; j < 3; ++j) {
            int k = tapg + 4 * j;
            if (k > 8) continue;               // wave-uniform branch
            int4 ix = rix[j];
            pf[j][0] = *(const uint4*)(xc + ix.x);
            pf[j][1] = *(const uint4*)(xc + ix.y);
            pf[j][2] = *(const uint4*)(xc + ix.z);
            pf[j][3] = *(const uint4*)(xc + ix.w);
        }
    };
    auto interp = [&](int buf) {
#pragma unroll
        for (int j = 0; j < 3; ++j) {
            int k = tapg + 4 * j;
            if (k > 8) continue;
            int cidx = k * 32 + spx;
            float4 wt = rwt[j];
            const unsigned* u00 = (const unsigned*)&pf[j][0];
            const unsigned* u01 = (const unsigned*)&pf[j][1];
            const unsigned* u10 = (const unsigned*)&pf[j][2];
            const unsigned* u11 = (const unsigned*)&pf[j][3];
            unsigned hv[4];
#pragma unroll
            for (int jj = 0; jj < 4; ++jj) {
                float2v s = unpk(u00[jj]) * wt.x;
                s += unpk(u01[jj]) * wt.y;
                s += unpk(u10[jj]) * wt.z;
                s += unpk(u11[jj]) * wt.w;
                hv[jj] = cvtpk_bf16(s.x, s.y);
            }
            *(uint4*)&V[buf * VBUF + cidx * VSTR + cg * 8]
                = make_uint4(hv[0], hv[1], hv[2], hv[3]);
        }
    };

    gload(0);                                  // prologue prefetch

    for (int cb = 0; cb < 8; ++cb) {
        const int buf = cb & 1;

        // ---- issue THIS cb's whi loads early (static addresses) ----
        short8 ah0[9], ah1[9];
#pragma unroll
        for (int k = 0; k < 9; ++k) {
            size_t base = ((size_t)((k * 8 + cb) * 256 + w * 32 + l15)) * 32 + q * 8;
            ah0[k] = *(const short8*)(whi + base);
            ah1[k] = *(const short8*)(whi + base + 16 * 32);
        }

        interp(buf);                           // consume pf -> V[buf] (VALU)
        if (cb < 7) gload(cb + 1);             // issue next-tile gathers
        __syncthreads();                       // V[buf] ready for all waves

        // ---- 9 MFMA chunks: pure LDS reads + MFMA (ah preloaded) ----
#pragma unroll
        for (int k = 0; k < 9; ++k) {
            short8 bh0 = *(const short8*)&V[buf * VBUF + (k * 32 + l15) * VSTR + q * 8];
            short8 bh1 = *(const short8*)&V[buf * VBUF + (k * 32 + 16 + l15) * VSTR + q * 8];
            acc[0][0] = __builtin_amdgcn_mfma_f32_16x16x32_bf16(ah0[k], bh0, acc[0][0], 0, 0, 0);
            acc[0][1] = __builtin_amdgcn_mfma_f32_16x16x32_bf16(ah0[k], bh1, acc[0][1], 0, 0, 0);
            acc[1][0] = __builtin_amdgcn_mfma_f32_16x16x32_bf16(ah1[k], bh0, acc[1][0], 0, 0, 0);
            acc[1][1] = __builtin_amdgcn_mfma_f32_16x16x32_bf16(ah1[k], bh1, acc[1][1], 0, 0, 0);
        }
        // no second barrier: next iter writes V[buf^1]
    }

    // ---- epilogue: plain stores (full K in this block) + bias ----
#pragma unroll
    for (int t = 0; t < 2; ++t) {
#pragma unroll
        for (int r = 0; r < 4; ++r) {
            int co = w * 32 + t * 16 + q * 4 + r;
            float bias = bdcn[co];
#pragma unroll
            for (int p = 0; p < 2; ++p) {
                int px = xh * 32 + p * 16 + l15;
                out[(((size_t)b * 256 + co) << 12) + y * 64 + px]
                    = acc[t][p][r] + bias;
            }
        }
    }
}

// ---------------------------------------------------------------------------
extern "C" void kernel_launch(void* const* d_in, const int* in_sizes, int n_in,
                              void* d_out, int out_size, void* d_ws, size_t ws_size,
                              hipStream_t stream)
{
    const float* x    = (const float*)d_in[0];
    const float* feat = (const float*)d_in[1];
    const float* wom  = (const float*)d_in[2];
    const float* bom  = (const float*)d_in[3];
    const float* wdcn = (const float*)d_in[4];
    const float* bdcn = (const float*)d_in[5];
    float* out = (float*)d_out;

    // workspace layout (all 16B-aligned)
    unsigned short* whi  = (unsigned short*)d_ws;                // 589824 sh
    unsigned short* wohi = whi + (size_t)CKTOT * 256;            // 73728 sh
    unsigned short* xTh  = wohi + 73728;                         // 2*4096*256
    unsigned short* fh   = xTh + (size_t)2 * HWPIX * 256;        // 2*4356*256

    prep_kernel<<<6056, 256, 0, stream>>>(x, feat, wdcn, wom, xTh, fh,
                                          whi, wohi);

    dim3 grid(128, 2);
    dcn_fused_kernel<<<grid, 512, 0, stream>>>(xTh, fh, whi, wohi,
                                               bom, bdcn, out);
}